// Round 7
// baseline (299.273 us; speedup 1.0000x reference)
//
#include <hip/hip_runtime.h>
#include <cstdint>
#include <cstddef>

#define N_TOK 4096
#define M_DIM 1024
#define APER  256
#define UNIF_START 3839   // rows >= this have no kept entries -> uniform 1/N

typedef __attribute__((ext_vector_type(8))) short short8;
typedef __attribute__((ext_vector_type(4))) float float4_t;

__device__ __forceinline__ unsigned short f2bf(float x) {
    union { float f; uint32_t u; } v; v.f = x;
    uint32_t u = v.u;
    u += 0x7FFFu + ((u >> 16) & 1u);   // round-to-nearest-even
    return (unsigned short)(u >> 16);
}

__device__ __forceinline__ void gload16(const void* g, void* l) {
    __builtin_amdgcn_global_load_lds(
        (const __attribute__((address_space(1))) void*)g,
        (__attribute__((address_space(3))) void*)l, 16, 0, 0);
}

// ---------------------------------------------------------------------------
// prep: one kernel for all input prep. 1-D grid of 8208 blocks:
//   [0,4096)       cast x fp32 -> bf16 (4M elems)
//   [4096,7168)    transpose+cast WK,WQ,Wout (3 x 1024 blocks of 32x32 tile)
//   [7168,8192)    cast WV -> bf16 (1M elems)
//   [8192,8208)    init rowsum (4096 floats)
// ---------------------------------------------------------------------------
__global__ __launch_bounds__(256) void prep(const float* __restrict__ x,
                                            const float* __restrict__ WK,
                                            const float* __restrict__ WQ,
                                            const float* __restrict__ WV,
                                            const float* __restrict__ Wout,
                                            unsigned short* __restrict__ xb,
                                            unsigned short* __restrict__ WKt,
                                            unsigned short* __restrict__ WQt,
                                            unsigned short* __restrict__ WVb,
                                            unsigned short* __restrict__ Woutt,
                                            float* __restrict__ rowsum) {
    const int bx = blockIdx.x;
    const int t  = threadIdx.x;
    __shared__ unsigned short tile[32][33];

    if (bx < 4096) {                       // cast x
        const int i = (bx * 256 + t) * 4;
        const float4 v = *reinterpret_cast<const float4*>(&x[i]);
        ushort4 o;
        o.x = f2bf(v.x); o.y = f2bf(v.y); o.z = f2bf(v.z); o.w = f2bf(v.w);
        *reinterpret_cast<ushort4*>(&xb[i]) = o;
        return;
    }
    if (bx < 7168) {                       // weight transposes
        const int z = (bx - 4096) >> 10;
        const int l = (bx - 4096) & 1023;
        const float* src = z == 0 ? WK : (z == 1 ? WQ : Wout);
        unsigned short* dst = z == 0 ? WKt : (z == 1 ? WQt : Woutt);
        const int c0 = (l & 31) * 32, r0 = (l >> 5) * 32;
        const int tx = t & 31, ty = t >> 5;
#pragma unroll
        for (int i = ty; i < 32; i += 8)
            tile[i][tx] = f2bf(src[(size_t)(r0 + i) * M_DIM + c0 + tx]);
        __syncthreads();
#pragma unroll
        for (int i = ty; i < 32; i += 8)
            dst[(size_t)(c0 + i) * M_DIM + r0 + tx] = tile[tx][i];
        return;
    }
    if (bx < 8192) {                       // cast WV
        const int i = ((bx - 7168) * 256 + t) * 4;
        const float4 v = *reinterpret_cast<const float4*>(&WV[i]);
        ushort4 o;
        o.x = f2bf(v.x); o.y = f2bf(v.y); o.z = f2bf(v.z); o.w = f2bf(v.w);
        *reinterpret_cast<ushort4*>(&WVb[i]) = o;
        return;
    }
    const int i = (bx - 8192) * 256 + t;   // init rowsum
    if (i < N_TOK) rowsum[i] = (i >= UNIF_START) ? (float)N_TOK : 0.0f;
}

// ---------------------------------------------------------------------------
// 64x64-tile NT GEMM (BK=32), proven core. SKIP==1: att^T zero-k skip.
// ---------------------------------------------------------------------------
template <int SKIP>
__global__ __launch_bounds__(256) void nt64sq(const unsigned short* __restrict__ A,
                                              const unsigned short* __restrict__ B,
                                              float* __restrict__ Cf,
                                              unsigned short* __restrict__ Cb,
                                              int N, int K) {
    const int by   = (SKIP == 1) ? ((int)gridDim.y - 1 - (int)blockIdx.y) : (int)blockIdx.y;
    const int row0 = by * 64;
    const int col0 = blockIdx.x * 64;

    __shared__ unsigned short Asb[64 * 32];
    __shared__ unsigned short Bsb[64 * 32];

    const int t = threadIdx.x, w = t >> 6, lane = t & 63;
    float4_t acc[4] = {};

    const int sr   = lane >> 2;
    const int sk   = ((lane & 3) ^ ((sr >> 1) & 3)) * 8;
    const int m    = lane & 15;
    const int slot = ((lane >> 4) ^ ((m >> 1) & 3)) * 8;

    for (int k0 = 0; k0 < K; k0 += 32) {
        if (SKIP == 1) {
            if ((k0 > row0 + 63 - APER - 1) && (k0 + 31 < UNIF_START)) continue;
        }
        const int rr = w * 16 + sr;
        gload16(&A[(size_t)(row0 + rr) * K + k0 + sk], &Asb[w * 512]);
        gload16(&B[(size_t)(col0 + rr) * K + k0 + sk], &Bsb[w * 512]);
        __syncthreads();
        const short8 af = *reinterpret_cast<const short8*>(&Asb[(w * 16 + m) * 32 + slot]);
        short8 bf[4];
#pragma unroll
        for (int j = 0; j < 4; ++j)
            bf[j] = *reinterpret_cast<const short8*>(&Bsb[(j * 16 + m) * 32 + slot]);
#pragma unroll
        for (int j = 0; j < 4; ++j)
            acc[j] = __builtin_amdgcn_mfma_f32_16x16x32_bf16(af, bf[j], acc[j], 0, 0, 0);
        __syncthreads();
    }

    const int crow = row0 + w * 16 + (lane >> 4) * 4;
    const int ccol = col0 + m;
#pragma unroll
    for (int j = 0; j < 4; ++j)
#pragma unroll
        for (int r = 0; r < 4; ++r) {
            const float v = acc[j][r];
            const size_t idx = (size_t)(crow + r) * N + ccol + j * 16;
            if (Cf) Cf[idx] = v;
            if (Cb) Cb[idx] = f2bf(v);
        }
}

// ---------------------------------------------------------------------------
// Fused QKV (proven BK=32 core): seg0 Kb, seg1 Qb (x0.06), seg2 emits VWt
// (transposed bf16, via LDS two-pass transpose) directly — no VWb write.
// ---------------------------------------------------------------------------
__global__ __launch_bounds__(256) void mfma_qkv(const unsigned short* __restrict__ xb,
                                                const unsigned short* __restrict__ WKt,
                                                const unsigned short* __restrict__ WQt,
                                                const unsigned short* __restrict__ WVWt,
                                                unsigned short* __restrict__ Kb,
                                                unsigned short* __restrict__ Qb,
                                                unsigned short* __restrict__ VWt) {
    const int row0  = blockIdx.y * 128;
    const int col0g = blockIdx.x * 128;
    const int seg   = col0g >> 10;
    const int col0  = col0g & 1023;
    const unsigned short* B = seg == 0 ? WKt : (seg == 1 ? WQt : WVWt);
    const float alpha = (seg == 1) ? 0.06f : 1.0f;

    __shared__ union {
        struct { unsigned short A[128 * 32]; unsigned short B[128 * 32]; } s;
        unsigned short T[64][136];  // transpose buffer (seg2 epilogue only)
    } sm;

    const int t = threadIdx.x, w = t >> 6, lane = t & 63;
    const int wr = (w >> 1) * 64, wc = (w & 1) * 64;

    float4_t acc[4][4] = {};

    const int sr   = lane >> 2;
    const int sk   = ((lane & 3) ^ ((sr >> 1) & 3)) * 8;
    const int m    = lane & 15;
    const int q    = lane >> 4;
    const int slot = (q ^ ((m >> 1) & 3)) * 8;

    for (int k0 = 0; k0 < M_DIM; k0 += 32) {
#pragma unroll
        for (int cc = 0; cc < 2; ++cc) {
            const int c = 2 * w + cc;
            const int rr = c * 16 + sr;
            gload16(&xb[(size_t)(row0 + rr) * M_DIM + k0 + sk], &sm.s.A[c * 512]);
            gload16(&B[(size_t)(col0 + rr) * M_DIM + k0 + sk], &sm.s.B[c * 512]);
        }
        __syncthreads();
        short8 af[4], bf[4];
#pragma unroll
        for (int i = 0; i < 4; ++i)
            af[i] = *reinterpret_cast<const short8*>(&sm.s.A[(wr + i * 16 + m) * 32 + slot]);
#pragma unroll
        for (int j = 0; j < 4; ++j)
            bf[j] = *reinterpret_cast<const short8*>(&sm.s.B[(wc + j * 16 + m) * 32 + slot]);
#pragma unroll
        for (int i = 0; i < 4; ++i)
#pragma unroll
            for (int j = 0; j < 4; ++j)
                acc[i][j] = __builtin_amdgcn_mfma_f32_16x16x32_bf16(af[i], bf[j], acc[i][j], 0, 0, 0);
        __syncthreads();
    }

    if (seg < 2) {
        unsigned short* C = seg == 0 ? Kb : Qb;
        const int crow = row0 + wr + q * 4;
        const int ccol = col0 + wc + m;
#pragma unroll
        for (int i = 0; i < 4; ++i)
#pragma unroll
            for (int j = 0; j < 4; ++j)
#pragma unroll
                for (int r = 0; r < 4; ++r)
                    C[(size_t)(crow + i * 16 + r) * M_DIM + ccol + j * 16] = f2bf(alpha * acc[i][j][r]);
        return;
    }

    // seg2: write VWt[c][i] = value at token row (i-dim), channel col (c-dim),
    // transposed via LDS, two passes over 64-col halves.
#pragma unroll
    for (int h = 0; h < 2; ++h) {
        __syncthreads();
        if ((w & 1) == h) {   // waves whose wc-half is h hold these columns
#pragma unroll
            for (int i = 0; i < 4; ++i)
#pragma unroll
                for (int j = 0; j < 4; ++j)
#pragma unroll
                    for (int r = 0; r < 4; ++r)
                        sm.T[m + j * 16][wr + q * 4 + i * 16 + r] = f2bf(acc[i][j][r]);
        }
        __syncthreads();
        // cooperative coalesced write: 64 rows (c) x 128 (i)
#pragma unroll
        for (int rr = 0; rr < 8; ++rr) {
            const int cl = w * 16 + rr * 2 + (lane >> 5);  // 2 rows per wave-instr
            const int il = (lane & 31) * 4;
            *reinterpret_cast<ushort4*>(&VWt[(size_t)(col0 + h * 64 + cl) * N_TOK + row0 + il]) =
                *reinterpret_cast<const ushort4*>(&sm.T[cl][il]);
        }
    }
}

// ---------------------------------------------------------------------------
// logits+exp: 64x128 tile (rows x cols), BK=32 proven core, aperture skip.
// att = E: masked->0, uniform rows->1, kept->exp(logit). Atomic rowsums.
// Grid (32, 64): ~930 active blocks (vs 465 at 128x128) for latency hiding.
// ---------------------------------------------------------------------------
__global__ __launch_bounds__(256) void mfma_logits_exp(const unsigned short* __restrict__ A,
                                                       const unsigned short* __restrict__ B,
                                                       float* __restrict__ att,
                                                       float* __restrict__ rowsum) {
    const int row0 = blockIdx.y * 64;
    const int col0 = blockIdx.x * 128;
    if (col0 + 127 <= row0 + APER) return; // fully masked tile

    __shared__ unsigned short Asb[64 * 32];
    __shared__ unsigned short Bsb[128 * 32];

    const int t = threadIdx.x, w = t >> 6, lane = t & 63;
    const int wr = (w >> 1) * 32, wc = (w & 1) * 64;

    float4_t acc[2][4] = {};

    const int sr   = lane >> 2;
    const int sk   = ((lane & 3) ^ ((sr >> 1) & 3)) * 8;
    const int m    = lane & 15;
    const int q    = lane >> 4;
    const int slot = (q ^ ((m >> 1) & 3)) * 8;

    for (int k0 = 0; k0 < M_DIM; k0 += 32) {
        {   // A: 4 chunks of 16 rows; wave w loads chunk w
            const int rr = w * 16 + sr;
            gload16(&A[(size_t)(row0 + rr) * M_DIM + k0 + sk], &Asb[w * 512]);
        }
#pragma unroll
        for (int cc = 0; cc < 2; ++cc) {
            const int c = 2 * w + cc;
            const int rr = c * 16 + sr;
            gload16(&B[(size_t)(col0 + rr) * M_DIM + k0 + sk], &Bsb[c * 512]);
        }
        __syncthreads();
        short8 af[2], bf[4];
#pragma unroll
        for (int i = 0; i < 2; ++i)
            af[i] = *reinterpret_cast<const short8*>(&Asb[(wr + i * 16 + m) * 32 + slot]);
#pragma unroll
        for (int j = 0; j < 4; ++j)
            bf[j] = *reinterpret_cast<const short8*>(&Bsb[(wc + j * 16 + m) * 32 + slot]);
#pragma unroll
        for (int i = 0; i < 2; ++i)
#pragma unroll
            for (int j = 0; j < 4; ++j)
                acc[i][j] = __builtin_amdgcn_mfma_f32_16x16x32_bf16(af[i], bf[j], acc[i][j], 0, 0, 0);
        __syncthreads();
    }

    const int crow = row0 + wr + q * 4;
    const int ccol = col0 + wc + m;
#pragma unroll
    for (int i = 0; i < 2; ++i) {
#pragma unroll
        for (int r = 0; r < 4; ++r) {
            const int gr = crow + i * 16 + r;
            float partial = 0.0f;
#pragma unroll
            for (int j = 0; j < 4; ++j) {
                const int gc = ccol + j * 16;
                float val;
                if (gr >= UNIF_START) {
                    val = 1.0f;
                } else if (gc > gr + APER) {
                    val = __expf(acc[i][j][r]);
                    partial += val;
                } else {
                    val = 0.0f;
                }
                att[(size_t)gr * N_TOK + gc] = val;
            }
            partial += __shfl_xor(partial, 1, 64);
            partial += __shfl_xor(partial, 2, 64);
            partial += __shfl_xor(partial, 4, 64);
            partial += __shfl_xor(partial, 8, 64);
            if (m == 0 && gr < UNIF_START) atomicAdd(&rowsum[gr], partial);
        }
    }
}

// ---------------------------------------------------------------------------
// finalize: att = E * inv (in place, fp32) + attT = bf16(att)^T.
// 64x64 tiles; trivial tiles (all masked/uniform) take a no-read fast path.
// Slow tiles (j0-i0 >= 256) always lie in logits-computed 64x128 tiles
// (col0-row0 >= 192 > 129), so E is always written there.
// ---------------------------------------------------------------------------
__global__ __launch_bounds__(256) void finalize_att(float* __restrict__ att,
                                                    unsigned short* __restrict__ attT,
                                                    const float* __restrict__ rowsum) {
    const int j0 = blockIdx.x * 64, i0 = blockIdx.y * 64;
    const int t = threadIdx.x;
    const int rl = t >> 4;             // 0..15
    const int c4 = (t & 15) * 4;       // 0,4,..,60
    const float u = 1.0f / (float)N_TOK;

    if (j0 + 63 <= i0 + APER) {        // trivial: masked rows -> 0, uniform -> u
#pragma unroll
        for (int s = 0; s < 4; ++s) {
            const int i = i0 + rl + 16 * s;
            const float val = (i >= UNIF_START) ? u : 0.0f;
            float4 v; v.x = v.y = v.z = v.w = val;
            *reinterpret_cast<float4*>(&att[(size_t)i * N_TOK + j0 + c4]) = v;
        }
        const unsigned short bu = f2bf(u);
#pragma unroll
        for (int s = 0; s < 4; ++s) {
            const int j = j0 + rl + 16 * s;
            ushort4 o;
            o.x = (i0 + c4 + 0 >= UNIF_START) ? bu : 0;
            o.y = (i0 + c4 + 1 >= UNIF_START) ? bu : 0;
            o.z = (i0 + c4 + 2 >= UNIF_START) ? bu : 0;
            o.w = (i0 + c4 + 3 >= UNIF_START) ? bu : 0;
            *reinterpret_cast<ushort4*>(&attT[(size_t)j * N_TOK + i0 + c4]) = o;
        }
        return;
    }

    __shared__ unsigned short tile[64][72];
#pragma unroll
    for (int s = 0; s < 4; ++s) {
        const int il = rl + 16 * s;
        const int i  = i0 + il;
        const float inv = 1.0f / rowsum[i];
        float4 v = *reinterpret_cast<const float4*>(&att[(size_t)i * N_TOK + j0 + c4]);
        v.x *= inv; v.y *= inv; v.z *= inv; v.w *= inv;
        *reinterpret_cast<float4*>(&att[(size_t)i * N_TOK + j0 + c4]) = v;
        ushort4 b;
        b.x = f2bf(v.x); b.y = f2bf(v.y); b.z = f2bf(v.z); b.w = f2bf(v.w);
        *reinterpret_cast<ushort4*>(&tile[il][c4]) = b;
    }
    __syncthreads();
#pragma unroll
    for (int s = 0; s < 4; ++s) {
        const int jl = rl + 16 * s;
        ushort4 o;
        o.x = tile[c4 + 0][jl];
        o.y = tile[c4 + 1][jl];
        o.z = tile[c4 + 2][jl];
        o.w = tile[c4 + 3][jl];
        *reinterpret_cast<ushort4*>(&attT[(size_t)(j0 + jl) * N_TOK + i0 + c4]) = o;
    }
}

extern "C" void kernel_launch(void* const* d_in, const int* in_sizes, int n_in,
                              void* d_out, int out_size, void* d_ws, size_t ws_size,
                              hipStream_t stream) {
    const float* x    = (const float*)d_in[0];
    const float* WK   = (const float*)d_in[1];
    const float* WQ   = (const float*)d_in[2];
    const float* WV   = (const float*)d_in[3];
    const float* Wout = (const float*)d_in[4];

    float* y   = (float*)d_out;                  // 4096 x 1024 fp32
    float* att = y + (size_t)N_TOK * M_DIM;      // 4096 x 4096 fp32 (E, then normalized)

    // ws layout (ushort elements); 1 MEG = 2 MB. Peak use 42 MB + 16 KB.
    unsigned short* base = (unsigned short*)d_ws;
    const size_t MEG = 1u << 20;
    unsigned short* xb    = base;             // [0,4)
    unsigned short* WKt   = base + 4  * MEG;  // [4,5)
    unsigned short* WQt   = base + 5  * MEG;  // [5,6)
    unsigned short* Woutt = base + 6  * MEG;  // [6,7)
    unsigned short* WVb   = base + 7  * MEG;  // [7,8)
    unsigned short* WVWt  = base + 8  * MEG;  // [8,9)
    unsigned short* Kb    = base + 9  * MEG;  // [9,13)
    unsigned short* Qb    = base + 13 * MEG;  // [13,17)
    unsigned short* VWt   = base + 17 * MEG;  // [17,21)  written transposed by qkv
    unsigned short* attT  = base;             // [0,16) overlays xb/wgts/Kb/Qb (dead by finalize)
    float*          rowsum = (float*)(base + 21 * MEG); // 16 KB

    const dim3 blk(256);

    // 1) all input prep in one kernel (+ rowsum init)
    prep<<<dim3(8208), blk, 0, stream>>>(x, WK, WQ, WV, Wout, xb, WKt, WQt, WVb, Woutt, rowsum);

    // 2) WVW^T = Wout^T @ WV^T  (folds Wout into the V projection)
    nt64sq<0><<<dim3(M_DIM / 64, M_DIM / 64), blk, 0, stream>>>(Woutt, WVb, nullptr, WVWt,
                                                                M_DIM, M_DIM);

    // 3) fused K/Q/VW projections; seg2 emits VWt (transposed) directly
    mfma_qkv<<<dim3(24, N_TOK / 128), blk, 0, stream>>>(xb, WKt, WQt, WVWt, Kb, Qb, VWt);

    // 4) logits -> masked exp E + row sums (64x128 tiles, ~3.6 active blocks/CU)
    mfma_logits_exp<<<dim3(N_TOK / 128, N_TOK / 64), blk, 0, stream>>>(Qb, Kb, att, rowsum);

    // 5) normalize att in place + build attT (bf16), fused
    finalize_att<<<dim3(N_TOK / 64, N_TOK / 64), blk, 0, stream>>>(att, attT, rowsum);

    // 6) y = att^T @ VW  (zero-k skip, heavy strips first)
    nt64sq<1><<<dim3(M_DIM / 64, N_TOK / 64), blk, 0, stream>>>(attT, VWt, y, nullptr,
                                                                M_DIM, N_TOK);
}